// Round 18
// baseline (179.483 us; speedup 1.0000x reference)
//
#include <hip/hip_runtime.h>

// Shapes (fixed): B=2, S=2048, E=1024, H=16, D=64, R=8, M=B*S=4096
typedef __attribute__((ext_vector_type(8))) _Float16 f16x8;
typedef __attribute__((ext_vector_type(4))) _Float16 f16x4;
typedef __attribute__((ext_vector_type(4))) float f32x4;

static __device__ __forceinline__ f16x4 pack4(float a, float b, float c, float d) {
    f16x4 r;
    auto p0 = __builtin_amdgcn_cvt_pkrtz(a, b);
    auto p1 = __builtin_amdgcn_cvt_pkrtz(c, d);
    r[0] = p0[0]; r[1] = p0[1]; r[2] = p1[0]; r[3] = p1[1];
    return r;
}

// async global->LDS, 16B per lane; LDS dest = wave-uniform base + lane*16
static __device__ __forceinline__ void gll16(const void* g, void* l) {
    __builtin_amdgcn_global_load_lds(
        (const __attribute__((address_space(1))) unsigned int*)g,
        (__attribute__((address_space(3))) unsigned int*)l, 16, 0, 0);
}

// ---------------- tsplit_w16: W fp32 [K][N] -> tiled swizzled fp16 [nb][kt][row][chunk] ----------------
// linear slot (row r, slot c) holds source chunk (c ^ (r&7)) -> staging is a pure linear DMA
__global__ __launch_bounds__(256) void tsplit_w16(const float* __restrict__ w0, const float* __restrict__ w1,
                                                  const float* __restrict__ w2, const float* __restrict__ w3,
                                                  _Float16* __restrict__ th) {
    const float* W = blockIdx.z == 0 ? w0 : blockIdx.z == 1 ? w1 : blockIdx.z == 2 ? w2 : w3;
    _Float16* oh = th + (size_t)blockIdx.z * 1048576;
    __shared__ float t[64][65];  // [n_local][k_local]
    const int tid = threadIdx.x;
    const int kt = blockIdx.x, nb = blockIdx.y;
    const int k0 = kt * 64, n0 = nb * 64;
    const int c = tid & 15, r = tid >> 4;
#pragma unroll
    for (int i = 0; i < 4; ++i) {
        const int row = r + i * 16;  // k-local
        const float4 v4 = *(const float4*)&W[(size_t)(k0 + row) * 1024 + n0 + c * 4];
        t[c * 4 + 0][row] = v4.x;
        t[c * 4 + 1][row] = v4.y;
        t[c * 4 + 2][row] = v4.z;
        t[c * 4 + 3][row] = v4.w;
    }
    __syncthreads();
    const size_t tb = (size_t)(nb * 16 + kt) * 4096;
#pragma unroll
    for (int i = 0; i < 2; ++i) {
        const int cid = tid * 2 + i;
        const int rr = cid >> 3, cc = cid & 7;
        const int ksrc = (cc ^ (rr & 7)) * 8;
        f16x8 hv;
#pragma unroll
        for (int j = 0; j < 8; ++j) hv[j] = (_Float16)t[rr][ksrc + j];
        *(f16x8*)&oh[tb + cid * 8] = hv;
    }
}

// ---------------- prep_lora: fused fp32->fp16 conversion + LoRA first stage ----------------
// y=0: q -> xaq + q16 (slot 0). y=1: v -> xav + v16 (slot 2). y=2: k -> k16 (slot 1).
__global__ __launch_bounds__(256) void prep_lora(const float* __restrict__ q, const float* __restrict__ kk,
                                                 const float* __restrict__ v,
                                                 const float* __restrict__ wqa, const float* __restrict__ wva,
                                                 float* __restrict__ xaq, float* __restrict__ xav,
                                                 _Float16* __restrict__ o16) {
    const int y = blockIdx.y;
    const float* X = y == 0 ? q : y == 1 ? v : kk;
    _Float16* O = o16 + (size_t)(y == 0 ? 0 : y == 1 ? 2 : 1) * 4194304;
    const float* WA = y == 0 ? wqa : wva;
    float* XA = y == 0 ? xaq : xav;
    const int tid = threadIdx.x;
    const int w = tid >> 6, lane = tid & 63;
    const int m = blockIdx.x * 4 + w;
    const float* xrow = X + (size_t)m * 1024;
    _Float16* orow = O + (size_t)m * 1024;
    float s[8] = {};
#pragma unroll
    for (int i = 0; i < 4; ++i) {
        const int k = lane * 4 + i * 256;
        const float4 x4 = *(const float4*)&xrow[k];
        *(f16x4*)&orow[k] = pack4(x4.x, x4.y, x4.z, x4.w);
        if (y < 2) {
            const float xs[4] = {x4.x, x4.y, x4.z, x4.w};
#pragma unroll
            for (int j = 0; j < 4; ++j) {
                const float* wr = WA + (size_t)(k + j) * 8;
                const float xv = xs[j];
#pragma unroll
                for (int rr = 0; rr < 8; ++rr) s[rr] = fmaf(xv, wr[rr], s[rr]);
            }
        }
    }
    if (y < 2) {
#pragma unroll
        for (int rr = 0; rr < 8; ++rr) {
            float vv = s[rr];
            vv += __shfl_xor(vv, 32);
            vv += __shfl_xor(vv, 16);
            vv += __shfl_xor(vv, 8);
            vv += __shfl_xor(vv, 4);
            vv += __shfl_xor(vv, 2);
            vv += __shfl_xor(vv, 1);
            if (lane == 0) XA[(size_t)m * 8 + rr] = vv;
        }
    }
}

// ---------------- fp16 MFMA GEMM v6: 128x64 block, 64x32 wave tile, gll staging ----------------
// A: fp16 [4096][1024] row-major. Bt: fp16 tiled swizzled. BK=64. 4 waves 2x2
// (wm: 64-row half, wn: 32-col half). Grid (32,16) = 512 blocks = 2/CU. LDS 48 KB dbuf.
// Per kc: 6 ds_read_b128 (A4+B2) feed 8 MFMAs — 0.75 reads/MFMA vs v3's 1.0.
// Fragment reads keep v3's 16-row lm pattern (conflict-free; r15's 32-row pattern was 8-way).
// OUT: 0 = fp32 [m][1024]; 1 = fp16 [B,H,S,D]; 2 = fp16 vT [B,H,D,S].
template <int OUT, bool LORA>
__global__ __launch_bounds__(256) void gemm_v6(const _Float16* __restrict__ A,
                                               const _Float16* __restrict__ Bt,
                                               const float* __restrict__ bias,
                                               const float* __restrict__ XA,
                                               const float* __restrict__ WB,
                                               float scale,
                                               void* __restrict__ outp) {
    __shared__ _Float16 Ahs[2][8192];  // [128 rows][64 k]
    __shared__ _Float16 Bhs[2][4096];  // [64 rows][64 k]
    const int tid = threadIdx.x;
    const int w = tid >> 6, l = tid & 63;
    const int lm = l & 15, g = l >> 4;
    const int wm = w >> 1, wn = w & 1;
    const int m0 = blockIdx.x * 128, nb = blockIdx.y;

    // staging: slot = j*256 + w*64 + l; row = j*32 + w*8 + (l>>3); row&7 == l>>3 (lane-constant)
    const int lr = l >> 3;
    const int ksw = ((l & 7) ^ lr) * 8;
    const _Float16* Asrc[4];
#pragma unroll
    for (int j = 0; j < 4; ++j) Asrc[j] = A + (size_t)(m0 + j * 32 + w * 8 + lr) * 1024 + ksw;
    const _Float16* Bsrc0 = Bt + (size_t)nb * 65536 + (w * 64 + l) * 8;        // pre-swizzled linear
    const _Float16* Bsrc1 = Bt + (size_t)nb * 65536 + (256 + w * 64 + l) * 8;
    const int ad[4] = {w * 512, 2048 + w * 512, 4096 + w * 512, 6144 + w * 512};
    const int bd0 = w * 512, bd1 = 2048 + w * 512;

    // fragment read offsets (row&7 == lm&7)
    int afo[4][2], bfo[2][2];
#pragma unroll
    for (int mt = 0; mt < 4; ++mt)
#pragma unroll
        for (int kc = 0; kc < 2; ++kc) {
            const int ar = wm * 64 + mt * 16 + lm;
            afo[mt][kc] = ar * 64 + (((kc * 4 + g) ^ (ar & 7)) * 8);
        }
#pragma unroll
    for (int nt = 0; nt < 2; ++nt)
#pragma unroll
        for (int kc = 0; kc < 2; ++kc) {
            const int br = wn * 32 + nt * 16 + lm;
            bfo[nt][kc] = br * 64 + (((kc * 4 + g) ^ (br & 7)) * 8);
        }

    f32x4 acc[4][2] = {};

#define STAGE(buf, kt)                                       \
    {                                                        \
        const int ko = (kt) * 64;                            \
        const int bo = (kt) * 4096;                          \
        _Pragma("unroll") for (int j = 0; j < 4; ++j)        \
            gll16(Asrc[j] + ko, &Ahs[buf][ad[j]]);           \
        gll16(Bsrc0 + bo, &Bhs[buf][bd0]);                   \
        gll16(Bsrc1 + bo, &Bhs[buf][bd1]);                   \
    }

    STAGE(0, 0)
    __syncthreads();

    for (int kt = 0; kt < 16; ++kt) {
        const int cur = kt & 1;
        if (kt < 15) STAGE(cur ^ 1, kt + 1)  // async loads fly during this tile's compute
        const _Float16* Ac = &Ahs[cur][0];
        const _Float16* Bc = &Bhs[cur][0];
#pragma unroll
        for (int kc = 0; kc < 2; ++kc) {
            f16x8 ah[4], bh[2];
#pragma unroll
            for (int i = 0; i < 4; ++i) ah[i] = *(const f16x8*)&Ac[afo[i][kc]];
#pragma unroll
            for (int i = 0; i < 2; ++i) bh[i] = *(const f16x8*)&Bc[bfo[i][kc]];
            __builtin_amdgcn_s_setprio(1);
#pragma unroll
            for (int mt = 0; mt < 4; ++mt)
#pragma unroll
                for (int nt = 0; nt < 2; ++nt)
                    acc[mt][nt] = __builtin_amdgcn_mfma_f32_16x16x32_f16(ah[mt], bh[nt], acc[mt][nt], 0, 0, 0);
            __builtin_amdgcn_s_setprio(0);
        }
        __syncthreads();  // drains vmcnt -> next buf ready; LDS reads of cur done
    }
#undef STAGE

    // epilogue: bias + optional LoRA + scale (v3's, mt 2->4, rows wm*64)
    const int nbase = nb * 64 + wn * 32;
    const int head = nb;
    float bias2[2];
#pragma unroll
    for (int nt = 0; nt < 2; ++nt) bias2[nt] = bias[nbase + nt * 16 + lm];
    float wbv[8][2];
    if (LORA) {
#pragma unroll
        for (int rr = 0; rr < 8; ++rr)
#pragma unroll
            for (int nt = 0; nt < 2; ++nt) wbv[rr][nt] = WB[rr * 1024 + nbase + nt * 16 + lm];
    }
#pragma unroll
    for (int mt = 0; mt < 4; ++mt) {
        float ov[2][4];
#pragma unroll
        for (int r = 0; r < 4; ++r) {
            const int m = m0 + wm * 64 + mt * 16 + g * 4 + r;
            float xa8[8];
            if (LORA) {
#pragma unroll
                for (int rr = 0; rr < 8; ++rr) xa8[rr] = XA[(size_t)m * 8 + rr];
            }
#pragma unroll
            for (int nt = 0; nt < 2; ++nt) {
                float o = acc[mt][nt][r] + bias2[nt];
                if (LORA) {
#pragma unroll
                    for (int rr = 0; rr < 8; ++rr) o = fmaf(xa8[rr], wbv[rr][nt], o);
                }
                o *= scale;
                ov[nt][r] = o;
                if (OUT == 0) {
                    ((float*)outp)[(size_t)m * 1024 + nbase + nt * 16 + lm] = o;
                } else if (OUT == 1) {
                    const int b = m >> 11, s = m & 2047;
                    ((_Float16*)outp)[((size_t)(b * 16 + head) * 2048 + s) * 64 + wn * 32 + nt * 16 + lm] = (_Float16)o;
                }
            }
        }
        if (OUT == 2) {
            const int b = m0 >> 11;
            const int sb = (m0 & 2047) + wm * 64 + mt * 16 + g * 4;
#pragma unroll
            for (int nt = 0; nt < 2; ++nt) {
                const int d = wn * 32 + nt * 16 + lm;
                const f16x4 pv = pack4(ov[nt][0], ov[nt][1], ov[nt][2], ov[nt][3]);
                *(f16x4*)&((_Float16*)outp)[((size_t)(b * 16 + head) * 64 + d) * 2048 + sb] = pv;
            }
        }
    }
}

// ---------------- flash attention v10: v9 compute + global_load_lds staging ----------------
// Staging produces a byte-identical LDS image to v9 (swizzle baked into per-lane global
// source, LDS dest linear), so all fragment read offsets are unchanged. 4 gll16/thread/tile
// replaces 4 global loads + 4 ds_writes + addressing VALU.
__global__ __launch_bounds__(256, 2) void flash_attn10(const _Float16* __restrict__ qh,
                                                       const _Float16* __restrict__ kh,
                                                       const _Float16* __restrict__ vT,
                                                       _Float16* __restrict__ ao) {
    __shared__ _Float16 Ks[2][4096];  // [kv][d], slot c holds source chunk c^(kv&7)
    __shared__ _Float16 Vs[2][4096];  // [d][kv], slot c holds source chunk c^(d&7)
    const int tid = threadIdx.x;
    const int w = tid >> 6, l = tid & 63;
    const int m = l & 15, g = l >> 4;
    const int bh = blockIdx.x & 31, qt = blockIdx.x >> 5;
    const _Float16* Qb = qh + (size_t)bh * 131072;
    const _Float16* Kb = kh + (size_t)bh * 131072;
    const _Float16* Vb = vT + (size_t)bh * 131072;
    const int q0 = qt * 128 + w * 32;

    f16x8 qf[2][2];
#pragma unroll
    for (int qg = 0; qg < 2; ++qg) {
        const _Float16* qrow = Qb + (size_t)(q0 + qg * 16 + m) * 64 + g * 8;
        qf[qg][0] = *(const f16x8*)(qrow);
        qf[qg][1] = *(const f16x8*)(qrow + 32);
    }

    // gll staging: slot = i*256 + w*64 + l -> row = i*32 + w*8 + (l>>3), chunk = l&7;
    // row&7 == l>>3 (lane-constant) -> swizzled source offset ksw.
    const int lr = l >> 3;
    const int ksw = ((l & 7) ^ lr) * 8;
    const _Float16* Ksrc0 = Kb + (size_t)(w * 8 + lr) * 64 + ksw;
    const _Float16* Ksrc1 = Kb + (size_t)(32 + w * 8 + lr) * 64 + ksw;
    const _Float16* Vsrc0 = Vb + (size_t)(w * 8 + lr) * 2048 + ksw;
    const _Float16* Vsrc1 = Vb + (size_t)(32 + w * 8 + lr) * 2048 + ksw;
    const int dst0 = w * 512, dst1 = 2048 + w * 512;  // wave-uniform LDS elem offsets

#define ASTG(buf, t)                                   \
    {                                                  \
        const int ko = (t) * 4096, vo = (t) * 64;      \
        gll16(Ksrc0 + ko, &Ks[buf][dst0]);             \
        gll16(Ksrc1 + ko, &Ks[buf][dst1]);             \
        gll16(Vsrc0 + vo, &Vs[buf][dst0]);             \
        gll16(Vsrc1 + vo, &Vs[buf][dst1]);             \
    }

    int koff[4][2];
#pragma unroll
    for (int nt = 0; nt < 4; ++nt)
#pragma unroll
        for (int kc = 0; kc < 2; ++kc) {
            const int kv = nt * 16 + m;
            koff[nt][kc] = kv * 64 + (((kc * 4 + g) ^ (kv & 7)) * 8);
        }
    int voff[4][4];
#pragma unroll
    for (int dt = 0; dt < 4; ++dt)
#pragma unroll
        for (int nt = 0; nt < 4; ++nt) {
            const int d = dt * 16 + m;
            voff[dt][nt] = d * 64 + (((nt * 2 + (g >> 1)) ^ (d & 7)) * 8) + (g & 1) * 4;
        }

    f32x4 acc_o[2][4] = {};
    f32x4 acc_l[2] = {};
    const f16x4 onesf = {(_Float16)1.f, (_Float16)1.f, (_Float16)1.f, (_Float16)1.f};

    ASTG(0, 0)
    __syncthreads();

    for (int t = 0; t < 32; ++t) {
        const int cur = t & 1;
        if (t < 31) ASTG(cur ^ 1, t + 1)  // async loads fly during this tile's compute

        const _Float16* Kc = &Ks[cur][0];
        const _Float16* Vc = &Vs[cur][0];

        f32x4 s[2][4] = {};
        __builtin_amdgcn_s_setprio(1);
#pragma unroll
        for (int nt = 0; nt < 4; ++nt)
#pragma unroll
            for (int kc = 0; kc < 2; ++kc) {
                const f16x8 kf = *(const f16x8*)(Kc + koff[nt][kc]);
                s[0][nt] = __builtin_amdgcn_mfma_f32_16x16x32_f16(kf, qf[0][kc], s[0][nt], 0, 0, 0);
                s[1][nt] = __builtin_amdgcn_mfma_f32_16x16x32_f16(kf, qf[1][kc], s[1][nt], 0, 0, 0);
            }
        __builtin_amdgcn_s_setprio(0);

        f16x4 pf[2][4];
#pragma unroll
        for (int qg = 0; qg < 2; ++qg)
#pragma unroll
            for (int nt = 0; nt < 4; ++nt)
                pf[qg][nt] = pack4(exp2f(s[qg][nt][0]), exp2f(s[qg][nt][1]),
                                   exp2f(s[qg][nt][2]), exp2f(s[qg][nt][3]));

        __builtin_amdgcn_s_setprio(1);
#pragma unroll
        for (int nt = 0; nt < 4; ++nt) {
            acc_l[0] = __builtin_amdgcn_mfma_f32_16x16x16f16(onesf, pf[0][nt], acc_l[0], 0, 0, 0);
            acc_l[1] = __builtin_amdgcn_mfma_f32_16x16x16f16(onesf, pf[1][nt], acc_l[1], 0, 0, 0);
#pragma unroll
            for (int dt = 0; dt < 4; ++dt) {
                const f16x4 vf = *(const f16x4*)(Vc + voff[dt][nt]);
                acc_o[0][dt] = __builtin_amdgcn_mfma_f32_16x16x16f16(vf, pf[0][nt], acc_o[0][dt], 0, 0, 0);
                acc_o[1][dt] = __builtin_amdgcn_mfma_f32_16x16x16f16(vf, pf[1][nt], acc_o[1][dt], 0, 0, 0);
            }
        }
        __builtin_amdgcn_s_setprio(0);

        __syncthreads();  // drains vmcnt (next buf staged) + lgkm (cur reads done)
    }
#undef ASTG

    const int b = bh >> 4, h = bh & 15;
#pragma unroll
    for (int qg = 0; qg < 2; ++qg) {
        const float inv = 1.f / acc_l[qg][0];
        const int srow = q0 + qg * 16 + m;
        _Float16* orow = ao + ((size_t)(b * 2048 + srow)) * 1024 + h * 64;
#pragma unroll
        for (int dt = 0; dt < 4; ++dt) {
            const f16x4 o = pack4(acc_o[qg][dt][0] * inv, acc_o[qg][dt][1] * inv,
                                  acc_o[qg][dt][2] * inv, acc_o[qg][dt][3] * inv);
            *(f16x4*)&orow[dt * 16 + g * 4] = o;
        }
    }
}

extern "C" void kernel_launch(void* const* d_in, const int* in_sizes, int n_in,
                              void* d_out, int out_size, void* d_ws, size_t ws_size,
                              hipStream_t stream) {
    const float* q    = (const float*)d_in[0];
    const float* k    = (const float*)d_in[1];
    const float* v    = (const float*)d_in[2];
    const float* wq   = (const float*)d_in[3];
    const float* bq   = (const float*)d_in[4];
    const float* wq_a = (const float*)d_in[5];
    const float* wq_b = (const float*)d_in[6];
    const float* wk   = (const float*)d_in[7];
    const float* bk   = (const float*)d_in[8];
    const float* wv   = (const float*)d_in[9];
    const float* bv   = (const float*)d_in[10];
    const float* wv_a = (const float*)d_in[11];
    const float* wv_b = (const float*)d_in[12];
    const float* wo   = (const float*)d_in[13];
    const float* bo   = (const float*)d_in[14];
    float* out = (float*)d_out;

    char* wsb = (char*)d_ws;
    _Float16* Wt   = (_Float16*)(wsb);                  // 8 MB: 4x tiled fp16 weights
    _Float16* a16  = (_Float16*)(wsb + (8u << 20));     // 24 MB: q16/k16/v16 fp16 [4096][1024]
    _Float16* aoF  = a16;                               // reuse q16 slot after Q-GEMM (dead)
    _Float16* qhF  = (_Float16*)(wsb + (32u << 20));    // 8 MB [B,H,S,D]
    _Float16* khF  = (_Float16*)(wsb + (40u << 20));    // 8 MB [B,H,S,D]
    _Float16* vTF  = (_Float16*)(wsb + (48u << 20));    // 8 MB [B,H,D,S]
    float* xaq     = (float*)(wsb + (56u << 20));       // 128 KB
    float* xav     = (float*)(wsb + (56u << 20) + (128u << 10));

    const dim3 ggrid(32, 16);
    const float qscale = 0.18033688f;  // (1/8) * log2(e)

    tsplit_w16<<<dim3(16, 16, 4), 256, 0, stream>>>(wq, wk, wv, wo, Wt);
    prep_lora<<<dim3(1024, 3), 256, 0, stream>>>(q, k, v, wq_a, wv_a, xaq, xav, a16);

    gemm_v6<1, true><<<ggrid, 256, 0, stream>>>(a16, Wt, bq, xaq, wq_b, qscale, qhF);
    gemm_v6<1, false><<<ggrid, 256, 0, stream>>>(a16 + 4194304, Wt + 1048576, bk, nullptr, nullptr, 1.f, khF);
    gemm_v6<2, true><<<ggrid, 256, 0, stream>>>(a16 + 8388608, Wt + 2097152, bv, xav, wv_b, 1.f, vTF);

    flash_attn10<<<512, 256, 0, stream>>>(qhF, khF, vTF, aoF);

    gemm_v6<0, false><<<ggrid, 256, 0, stream>>>(aoF, Wt + 3145728, bo, nullptr, nullptr, 1.f, out);
}

// Round 19
// 161.790 us; speedup vs baseline: 1.1094x; 1.1094x over previous
//
#include <hip/hip_runtime.h>

// Shapes (fixed): B=2, S=2048, E=1024, H=16, D=64, R=8, M=B*S=4096
typedef __attribute__((ext_vector_type(8))) _Float16 f16x8;
typedef __attribute__((ext_vector_type(4))) _Float16 f16x4;
typedef __attribute__((ext_vector_type(4))) float f32x4;

static __device__ __forceinline__ f16x4 pack4(float a, float b, float c, float d) {
    f16x4 r;
    auto p0 = __builtin_amdgcn_cvt_pkrtz(a, b);
    auto p1 = __builtin_amdgcn_cvt_pkrtz(c, d);
    r[0] = p0[0]; r[1] = p0[1]; r[2] = p1[0]; r[3] = p1[1];
    return r;
}

// async global->LDS, 16B per lane; LDS dest = wave-uniform base + lane*16
static __device__ __forceinline__ void gll16(const void* g, void* l) {
    __builtin_amdgcn_global_load_lds(
        (const __attribute__((address_space(1))) unsigned int*)g,
        (__attribute__((address_space(3))) unsigned int*)l, 16, 0, 0);
}

// ---------------- tsplit_w16: W fp32 [K][N] -> tiled swizzled fp16 [nb][kt][row][chunk] ----------------
// linear slot (row r, slot c) holds source chunk (c ^ (r&7)) -> staging is a pure linear DMA
__global__ __launch_bounds__(256) void tsplit_w16(const float* __restrict__ w0, const float* __restrict__ w1,
                                                  const float* __restrict__ w2, const float* __restrict__ w3,
                                                  _Float16* __restrict__ th) {
    const float* W = blockIdx.z == 0 ? w0 : blockIdx.z == 1 ? w1 : blockIdx.z == 2 ? w2 : w3;
    _Float16* oh = th + (size_t)blockIdx.z * 1048576;
    __shared__ float t[64][65];  // [n_local][k_local]
    const int tid = threadIdx.x;
    const int kt = blockIdx.x, nb = blockIdx.y;
    const int k0 = kt * 64, n0 = nb * 64;
    const int c = tid & 15, r = tid >> 4;
#pragma unroll
    for (int i = 0; i < 4; ++i) {
        const int row = r + i * 16;  // k-local
        const float4 v4 = *(const float4*)&W[(size_t)(k0 + row) * 1024 + n0 + c * 4];
        t[c * 4 + 0][row] = v4.x;
        t[c * 4 + 1][row] = v4.y;
        t[c * 4 + 2][row] = v4.z;
        t[c * 4 + 3][row] = v4.w;
    }
    __syncthreads();
    const size_t tb = (size_t)(nb * 16 + kt) * 4096;
#pragma unroll
    for (int i = 0; i < 2; ++i) {
        const int cid = tid * 2 + i;
        const int rr = cid >> 3, cc = cid & 7;
        const int ksrc = (cc ^ (rr & 7)) * 8;
        f16x8 hv;
#pragma unroll
        for (int j = 0; j < 8; ++j) hv[j] = (_Float16)t[rr][ksrc + j];
        *(f16x8*)&oh[tb + cid * 8] = hv;
    }
}

// ---------------- prep_lora: fused fp32->fp16 conversion + LoRA first stage ----------------
// y=0: q -> xaq + q16 (slot 0). y=1: v -> xav + v16 (slot 2). y=2: k -> k16 (slot 1).
__global__ __launch_bounds__(256) void prep_lora(const float* __restrict__ q, const float* __restrict__ kk,
                                                 const float* __restrict__ v,
                                                 const float* __restrict__ wqa, const float* __restrict__ wva,
                                                 float* __restrict__ xaq, float* __restrict__ xav,
                                                 _Float16* __restrict__ o16) {
    const int y = blockIdx.y;
    const float* X = y == 0 ? q : y == 1 ? v : kk;
    _Float16* O = o16 + (size_t)(y == 0 ? 0 : y == 1 ? 2 : 1) * 4194304;
    const float* WA = y == 0 ? wqa : wva;
    float* XA = y == 0 ? xaq : xav;
    const int tid = threadIdx.x;
    const int w = tid >> 6, lane = tid & 63;
    const int m = blockIdx.x * 4 + w;
    const float* xrow = X + (size_t)m * 1024;
    _Float16* orow = O + (size_t)m * 1024;
    float s[8] = {};
#pragma unroll
    for (int i = 0; i < 4; ++i) {
        const int k = lane * 4 + i * 256;
        const float4 x4 = *(const float4*)&xrow[k];
        *(f16x4*)&orow[k] = pack4(x4.x, x4.y, x4.z, x4.w);
        if (y < 2) {
            const float xs[4] = {x4.x, x4.y, x4.z, x4.w};
#pragma unroll
            for (int j = 0; j < 4; ++j) {
                const float* wr = WA + (size_t)(k + j) * 8;
                const float xv = xs[j];
#pragma unroll
                for (int rr = 0; rr < 8; ++rr) s[rr] = fmaf(xv, wr[rr], s[rr]);
            }
        }
    }
    if (y < 2) {
#pragma unroll
        for (int rr = 0; rr < 8; ++rr) {
            float vv = s[rr];
            vv += __shfl_xor(vv, 32);
            vv += __shfl_xor(vv, 16);
            vv += __shfl_xor(vv, 8);
            vv += __shfl_xor(vv, 4);
            vv += __shfl_xor(vv, 2);
            vv += __shfl_xor(vv, 1);
            if (lane == 0) XA[(size_t)m * 8 + rr] = vv;
        }
    }
}

// ---------------- merged QKV GEMM: r16's gemm_v3 body, z selects input/output ----------------
// z=0: q16 -> qhF (fp16 [B,H,S,D], LoRA, pre-scaled). z=1: k16 -> khF (no LoRA).
// z=2: v16 -> vTF (fp16 [B,H,D,S], LoRA). Grid (64,16,3) = 3072 blocks, one dispatch:
// the no-LoRA K section's tail overlaps V's head instead of a dispatch boundary.
__global__ __launch_bounds__(256) void qkv_gemm(const _Float16* __restrict__ a16,
                                                const _Float16* __restrict__ Wt,
                                                const float* __restrict__ bq, const float* __restrict__ bk,
                                                const float* __restrict__ bv,
                                                const float* __restrict__ xaq, const float* __restrict__ xav,
                                                const float* __restrict__ wqb, const float* __restrict__ wvb,
                                                float qscale,
                                                _Float16* __restrict__ qhF, _Float16* __restrict__ khF,
                                                _Float16* __restrict__ vTF) {
    const int z = blockIdx.z;
    const _Float16* A = a16 + (size_t)z * 4194304;
    const _Float16* Bt = Wt + (size_t)z * 1048576;
    const float* bias = z == 0 ? bq : z == 1 ? bk : bv;
    const float* XA = z == 0 ? xaq : xav;
    const float* WB = z == 0 ? wqb : wvb;
    const float scale = z == 0 ? qscale : 1.f;
    const bool lora = (z != 1);
    _Float16* outp = z == 0 ? qhF : z == 1 ? khF : vTF;

    __shared__ _Float16 Ahs[2][4096], Bhs[2][4096];
    const int tid = threadIdx.x;
    const int w = tid >> 6, l = tid & 63;
    const int lm = l & 15, g = l >> 4;
    const int wm = w >> 1, wn = w & 1;
    const int m0 = blockIdx.x * 64, nb = blockIdx.y;

    const int lr = l >> 3;
    const int ksw = ((l & 7) ^ lr) * 8;
    const _Float16* Asrc0 = A + (size_t)(m0 + w * 16 + lr) * 1024 + ksw;
    const _Float16* Asrc1 = A + (size_t)(m0 + w * 16 + 8 + lr) * 1024 + ksw;
    const _Float16* Bsrc0 = Bt + (size_t)nb * 65536 + (w * 128 + l) * 8;
    const _Float16* Bsrc1 = Bt + (size_t)nb * 65536 + (w * 128 + 64 + l) * 8;
    const int adst0 = w * 1024, adst1 = w * 1024 + 512;

    int afo[2][2], bfo[2][2];
#pragma unroll
    for (int t = 0; t < 2; ++t)
#pragma unroll
        for (int kc = 0; kc < 2; ++kc) {
            const int ar = wm * 32 + t * 16 + lm;
            const int br = wn * 32 + t * 16 + lm;
            afo[t][kc] = ar * 64 + (((kc * 4 + g) ^ (ar & 7)) * 8);
            bfo[t][kc] = br * 64 + (((kc * 4 + g) ^ (br & 7)) * 8);
        }

    f32x4 acc[2][2] = {};

#define STAGE(buf, kt)                                  \
    {                                                   \
        const int ko = (kt) * 64;                       \
        const int bo = (kt) * 4096;                     \
        gll16(Asrc0 + ko, &Ahs[buf][adst0]);            \
        gll16(Asrc1 + ko, &Ahs[buf][adst1]);            \
        gll16(Bsrc0 + bo, &Bhs[buf][adst0]);            \
        gll16(Bsrc1 + bo, &Bhs[buf][adst1]);            \
    }

    STAGE(0, 0)
    __syncthreads();

    for (int kt = 0; kt < 16; ++kt) {
        const int cur = kt & 1;
        if (kt < 15) STAGE(cur ^ 1, kt + 1)
        const _Float16* Ac = &Ahs[cur][0];
        const _Float16* Bc = &Bhs[cur][0];
#pragma unroll
        for (int kc = 0; kc < 2; ++kc) {
            f16x8 ah[2], bh[2];
#pragma unroll
            for (int i = 0; i < 2; ++i) {
                ah[i] = *(const f16x8*)&Ac[afo[i][kc]];
                bh[i] = *(const f16x8*)&Bc[bfo[i][kc]];
            }
            __builtin_amdgcn_s_setprio(1);
#pragma unroll
            for (int mt = 0; mt < 2; ++mt)
#pragma unroll
                for (int nt = 0; nt < 2; ++nt)
                    acc[mt][nt] = __builtin_amdgcn_mfma_f32_16x16x32_f16(ah[mt], bh[nt], acc[mt][nt], 0, 0, 0);
            __builtin_amdgcn_s_setprio(0);
        }
        __syncthreads();
    }
#undef STAGE

    const int nbase = nb * 64 + wn * 32;
    const int head = nb;
    float bias2[2];
#pragma unroll
    for (int nt = 0; nt < 2; ++nt) bias2[nt] = bias[nbase + nt * 16 + lm];
    float wbv[8][2];
    if (lora) {
#pragma unroll
        for (int rr = 0; rr < 8; ++rr)
#pragma unroll
            for (int nt = 0; nt < 2; ++nt) wbv[rr][nt] = WB[rr * 1024 + nbase + nt * 16 + lm];
    }
#pragma unroll
    for (int mt = 0; mt < 2; ++mt) {
        float ov[2][4];
#pragma unroll
        for (int r = 0; r < 4; ++r) {
            const int m = m0 + wm * 32 + mt * 16 + g * 4 + r;
            float xa8[8];
            if (lora) {
#pragma unroll
                for (int rr = 0; rr < 8; ++rr) xa8[rr] = XA[(size_t)m * 8 + rr];
            }
#pragma unroll
            for (int nt = 0; nt < 2; ++nt) {
                float o = acc[mt][nt][r] + bias2[nt];
                if (lora) {
#pragma unroll
                    for (int rr = 0; rr < 8; ++rr) o = fmaf(xa8[rr], wbv[rr][nt], o);
                }
                o *= scale;
                ov[nt][r] = o;
                if (z != 2) {
                    const int b = m >> 11, s = m & 2047;
                    outp[((size_t)(b * 16 + head) * 2048 + s) * 64 + wn * 32 + nt * 16 + lm] = (_Float16)o;
                }
            }
        }
        if (z == 2) {
            const int b = m0 >> 11;
            const int sb = (m0 & 2047) + wm * 32 + mt * 16 + g * 4;
#pragma unroll
            for (int nt = 0; nt < 2; ++nt) {
                const int d = wn * 32 + nt * 16 + lm;
                const f16x4 pv = pack4(ov[nt][0], ov[nt][1], ov[nt][2], ov[nt][3]);
                *(f16x4*)&outp[((size_t)(b * 16 + head) * 64 + d) * 2048 + sb] = pv;
            }
        }
    }
}

// ---------------- output-projection GEMM (r16's gemm_v3, OUT=0 path only) ----------------
__global__ __launch_bounds__(256) void gemm_wo(const _Float16* __restrict__ A,
                                               const _Float16* __restrict__ Bt,
                                               const float* __restrict__ bias,
                                               float* __restrict__ outp) {
    __shared__ _Float16 Ahs[2][4096], Bhs[2][4096];
    const int tid = threadIdx.x;
    const int w = tid >> 6, l = tid & 63;
    const int lm = l & 15, g = l >> 4;
    const int wm = w >> 1, wn = w & 1;
    const int m0 = blockIdx.x * 64, nb = blockIdx.y;

    const int lr = l >> 3;
    const int ksw = ((l & 7) ^ lr) * 8;
    const _Float16* Asrc0 = A + (size_t)(m0 + w * 16 + lr) * 1024 + ksw;
    const _Float16* Asrc1 = A + (size_t)(m0 + w * 16 + 8 + lr) * 1024 + ksw;
    const _Float16* Bsrc0 = Bt + (size_t)nb * 65536 + (w * 128 + l) * 8;
    const _Float16* Bsrc1 = Bt + (size_t)nb * 65536 + (w * 128 + 64 + l) * 8;
    const int adst0 = w * 1024, adst1 = w * 1024 + 512;

    int afo[2][2], bfo[2][2];
#pragma unroll
    for (int t = 0; t < 2; ++t)
#pragma unroll
        for (int kc = 0; kc < 2; ++kc) {
            const int ar = wm * 32 + t * 16 + lm;
            const int br = wn * 32 + t * 16 + lm;
            afo[t][kc] = ar * 64 + (((kc * 4 + g) ^ (ar & 7)) * 8);
            bfo[t][kc] = br * 64 + (((kc * 4 + g) ^ (br & 7)) * 8);
        }

    f32x4 acc[2][2] = {};

#define STAGE(buf, kt)                                  \
    {                                                   \
        const int ko = (kt) * 64;                       \
        const int bo = (kt) * 4096;                     \
        gll16(Asrc0 + ko, &Ahs[buf][adst0]);            \
        gll16(Asrc1 + ko, &Ahs[buf][adst1]);            \
        gll16(Bsrc0 + bo, &Bhs[buf][adst0]);            \
        gll16(Bsrc1 + bo, &Bhs[buf][adst1]);            \
    }

    STAGE(0, 0)
    __syncthreads();

    for (int kt = 0; kt < 16; ++kt) {
        const int cur = kt & 1;
        if (kt < 15) STAGE(cur ^ 1, kt + 1)
        const _Float16* Ac = &Ahs[cur][0];
        const _Float16* Bc = &Bhs[cur][0];
#pragma unroll
        for (int kc = 0; kc < 2; ++kc) {
            f16x8 ah[2], bh[2];
#pragma unroll
            for (int i = 0; i < 2; ++i) {
                ah[i] = *(const f16x8*)&Ac[afo[i][kc]];
                bh[i] = *(const f16x8*)&Bc[bfo[i][kc]];
            }
            __builtin_amdgcn_s_setprio(1);
#pragma unroll
            for (int mt = 0; mt < 2; ++mt)
#pragma unroll
                for (int nt = 0; nt < 2; ++nt)
                    acc[mt][nt] = __builtin_amdgcn_mfma_f32_16x16x32_f16(ah[mt], bh[nt], acc[mt][nt], 0, 0, 0);
            __builtin_amdgcn_s_setprio(0);
        }
        __syncthreads();
    }
#undef STAGE

    const int nbase = nb * 64 + wn * 32;
    float bias2[2];
#pragma unroll
    for (int nt = 0; nt < 2; ++nt) bias2[nt] = bias[nbase + nt * 16 + lm];
#pragma unroll
    for (int mt = 0; mt < 2; ++mt) {
#pragma unroll
        for (int r = 0; r < 4; ++r) {
            const int m = m0 + wm * 32 + mt * 16 + g * 4 + r;
#pragma unroll
            for (int nt = 0; nt < 2; ++nt)
                outp[(size_t)m * 1024 + nbase + nt * 16 + lm] = acc[mt][nt][r] + bias2[nt];
        }
    }
}

// ---------------- flash attention v9 (r14/r16 verified, unchanged) ----------------
__global__ __launch_bounds__(256, 2) void flash_attn9(const _Float16* __restrict__ qh,
                                                      const _Float16* __restrict__ kh,
                                                      const _Float16* __restrict__ vT,
                                                      _Float16* __restrict__ ao) {
    __shared__ _Float16 Ks[2][4096];  // [kv][d], 16B chunk ^= kv&7
    __shared__ _Float16 Vs[2][4096];  // [d][kv], 16B chunk ^= d&7
    const int tid = threadIdx.x;
    const int w = tid >> 6, l = tid & 63;
    const int m = l & 15, g = l >> 4;
    const int bh = blockIdx.x & 31, qt = blockIdx.x >> 5;
    const _Float16* Qb = qh + (size_t)bh * 131072;
    const _Float16* Kb = kh + (size_t)bh * 131072;
    const _Float16* Vb = vT + (size_t)bh * 131072;
    const int q0 = qt * 128 + w * 32;

    f16x8 qf[2][2];
#pragma unroll
    for (int qg = 0; qg < 2; ++qg) {
        const _Float16* qrow = Qb + (size_t)(q0 + qg * 16 + m) * 64 + g * 8;
        qf[qg][0] = *(const f16x8*)(qrow);
        qf[qg][1] = *(const f16x8*)(qrow + 32);
    }

    const int r0 = tid >> 3, c0 = tid & 7;
    const int r1 = (tid + 256) >> 3;
    const int kgl0 = r0 * 64 + c0 * 8;
    const int kgl1 = r1 * 64 + c0 * 8;
    const int kso0 = r0 * 64 + ((c0 ^ (r0 & 7)) * 8);
    const int kso1 = r1 * 64 + ((c0 ^ (r1 & 7)) * 8);
    const size_t vgl0 = (size_t)r0 * 2048 + c0 * 8;
    const size_t vgl1 = (size_t)r1 * 2048 + c0 * 8;

    int koff[4][2];
#pragma unroll
    for (int nt = 0; nt < 4; ++nt)
#pragma unroll
        for (int kc = 0; kc < 2; ++kc) {
            const int kv = nt * 16 + m;
            koff[nt][kc] = kv * 64 + (((kc * 4 + g) ^ (kv & 7)) * 8);
        }
    int voff[4][4];
#pragma unroll
    for (int dt = 0; dt < 4; ++dt)
#pragma unroll
        for (int nt = 0; nt < 4; ++nt) {
            const int d = dt * 16 + m;
            voff[dt][nt] = d * 64 + (((nt * 2 + (g >> 1)) ^ (d & 7)) * 8) + (g & 1) * 4;
        }

    f32x4 acc_o[2][4] = {};
    f32x4 acc_l[2] = {};
    const f16x4 onesf = {(_Float16)1.f, (_Float16)1.f, (_Float16)1.f, (_Float16)1.f};

    {
        const f16x8 ka = *(const f16x8*)(Kb + kgl0);
        const f16x8 kb2 = *(const f16x8*)(Kb + kgl1);
        const f16x8 va = *(const f16x8*)(Vb + vgl0);
        const f16x8 vb2 = *(const f16x8*)(Vb + vgl1);
        *(f16x8*)(&Ks[0][0] + kso0) = ka;
        *(f16x8*)(&Ks[0][0] + kso1) = kb2;
        *(f16x8*)(&Vs[0][0] + kso0) = va;
        *(f16x8*)(&Vs[0][0] + kso1) = vb2;
    }
    __syncthreads();

    for (int t = 0; t < 32; ++t) {
        const int cur = t & 1;
        f16x8 ka, kb2, va, vb2;
        if (t < 31) {
            const int koI = (t + 1) * 4096;
            const int voI = (t + 1) * 64;
            ka = *(const f16x8*)(Kb + koI + kgl0);
            kb2 = *(const f16x8*)(Kb + koI + kgl1);
            va = *(const f16x8*)(Vb + voI + vgl0);
            vb2 = *(const f16x8*)(Vb + voI + vgl1);
        }

        const _Float16* Kc = &Ks[cur][0];
        const _Float16* Vc = &Vs[cur][0];

        f32x4 s[2][4] = {};
        __builtin_amdgcn_s_setprio(1);
#pragma unroll
        for (int nt = 0; nt < 4; ++nt)
#pragma unroll
            for (int kc = 0; kc < 2; ++kc) {
                const f16x8 kf = *(const f16x8*)(Kc + koff[nt][kc]);
                s[0][nt] = __builtin_amdgcn_mfma_f32_16x16x32_f16(kf, qf[0][kc], s[0][nt], 0, 0, 0);
                s[1][nt] = __builtin_amdgcn_mfma_f32_16x16x32_f16(kf, qf[1][kc], s[1][nt], 0, 0, 0);
            }
        __builtin_amdgcn_s_setprio(0);

        f16x4 pf[2][4];
#pragma unroll
        for (int qg = 0; qg < 2; ++qg)
#pragma unroll
            for (int nt = 0; nt < 4; ++nt)
                pf[qg][nt] = pack4(exp2f(s[qg][nt][0]), exp2f(s[qg][nt][1]),
                                   exp2f(s[qg][nt][2]), exp2f(s[qg][nt][3]));

        __builtin_amdgcn_s_setprio(1);
#pragma unroll
        for (int nt = 0; nt < 4; ++nt) {
            acc_l[0] = __builtin_amdgcn_mfma_f32_16x16x16f16(onesf, pf[0][nt], acc_l[0], 0, 0, 0);
            acc_l[1] = __builtin_amdgcn_mfma_f32_16x16x16f16(onesf, pf[1][nt], acc_l[1], 0, 0, 0);
#pragma unroll
            for (int dt = 0; dt < 4; ++dt) {
                const f16x4 vf = *(const f16x4*)(Vc + voff[dt][nt]);
                acc_o[0][dt] = __builtin_amdgcn_mfma_f32_16x16x16f16(vf, pf[0][nt], acc_o[0][dt], 0, 0, 0);
                acc_o[1][dt] = __builtin_amdgcn_mfma_f32_16x16x16f16(vf, pf[1][nt], acc_o[1][dt], 0, 0, 0);
            }
        }
        __builtin_amdgcn_s_setprio(0);

        if (t < 31) {
            const int nxt = cur ^ 1;
            *(f16x8*)(&Ks[nxt][0] + kso0) = ka;
            *(f16x8*)(&Ks[nxt][0] + kso1) = kb2;
            *(f16x8*)(&Vs[nxt][0] + kso0) = va;
            *(f16x8*)(&Vs[nxt][0] + kso1) = vb2;
        }
        __syncthreads();
    }

    const int b = bh >> 4, h = bh & 15;
#pragma unroll
    for (int qg = 0; qg < 2; ++qg) {
        const float inv = 1.f / acc_l[qg][0];
        const int srow = q0 + qg * 16 + m;
        _Float16* orow = ao + ((size_t)(b * 2048 + srow)) * 1024 + h * 64;
#pragma unroll
        for (int dt = 0; dt < 4; ++dt) {
            const f16x4 o = pack4(acc_o[qg][dt][0] * inv, acc_o[qg][dt][1] * inv,
                                  acc_o[qg][dt][2] * inv, acc_o[qg][dt][3] * inv);
            *(f16x4*)&orow[dt * 16 + g * 4] = o;
        }
    }
}

extern "C" void kernel_launch(void* const* d_in, const int* in_sizes, int n_in,
                              void* d_out, int out_size, void* d_ws, size_t ws_size,
                              hipStream_t stream) {
    const float* q    = (const float*)d_in[0];
    const float* k    = (const float*)d_in[1];
    const float* v    = (const float*)d_in[2];
    const float* wq   = (const float*)d_in[3];
    const float* bq   = (const float*)d_in[4];
    const float* wq_a = (const float*)d_in[5];
    const float* wq_b = (const float*)d_in[6];
    const float* wk   = (const float*)d_in[7];
    const float* bk   = (const float*)d_in[8];
    const float* wv   = (const float*)d_in[9];
    const float* bv   = (const float*)d_in[10];
    const float* wv_a = (const float*)d_in[11];
    const float* wv_b = (const float*)d_in[12];
    const float* wo   = (const float*)d_in[13];
    const float* bo   = (const float*)d_in[14];
    float* out = (float*)d_out;

    char* wsb = (char*)d_ws;
    _Float16* Wt   = (_Float16*)(wsb);                  // 8 MB: 4x tiled fp16 weights
    _Float16* a16  = (_Float16*)(wsb + (8u << 20));     // 24 MB: q16/k16/v16 fp16 [4096][1024]
    _Float16* aoF  = a16;                               // reuse q16 slot after Q-GEMM (dead)
    _Float16* qhF  = (_Float16*)(wsb + (32u << 20));    // 8 MB [B,H,S,D]
    _Float16* khF  = (_Float16*)(wsb + (40u << 20));    // 8 MB [B,H,S,D]
    _Float16* vTF  = (_Float16*)(wsb + (48u << 20));    // 8 MB [B,H,D,S]
    float* xaq     = (float*)(wsb + (56u << 20));       // 128 KB
    float* xav     = (float*)(wsb + (56u << 20) + (128u << 10));

    const float qscale = 0.18033688f;  // (1/8) * log2(e)

    tsplit_w16<<<dim3(16, 16, 4), 256, 0, stream>>>(wq, wk, wv, wo, Wt);
    prep_lora<<<dim3(1024, 3), 256, 0, stream>>>(q, k, v, wq_a, wv_a, xaq, xav, a16);

    qkv_gemm<<<dim3(64, 16, 3), 256, 0, stream>>>(a16, Wt, bq, bk, bv, xaq, xav,
                                                  wq_b, wv_b, qscale, qhF, khF, vTF);

    flash_attn9<<<512, 256, 0, stream>>>(qhF, khF, vTF, aoF);

    gemm_wo<<<dim3(64, 16), 256, 0, stream>>>(aoF, Wt + 3145728, bo, out);
}

// Round 20
// 157.281 us; speedup vs baseline: 1.1412x; 1.0287x over previous
//
#include <hip/hip_runtime.h>

// Shapes (fixed): B=2, S=2048, E=1024, H=16, D=64, R=8, M=B*S=4096
typedef __attribute__((ext_vector_type(8))) _Float16 f16x8;
typedef __attribute__((ext_vector_type(4))) _Float16 f16x4;
typedef __attribute__((ext_vector_type(4))) float f32x4;

static __device__ __forceinline__ f16x4 pack4(float a, float b, float c, float d) {
    f16x4 r;
    auto p0 = __builtin_amdgcn_cvt_pkrtz(a, b);
    auto p1 = __builtin_amdgcn_cvt_pkrtz(c, d);
    r[0] = p0[0]; r[1] = p0[1]; r[2] = p1[0]; r[3] = p1[1];
    return r;
}

// async global->LDS, 16B per lane; LDS dest = wave-uniform base + lane*16
static __device__ __forceinline__ void gll16(const void* g, void* l) {
    __builtin_amdgcn_global_load_lds(
        (const __attribute__((address_space(1))) unsigned int*)g,
        (__attribute__((address_space(3))) unsigned int*)l, 16, 0, 0);
}

// ---------------- prep_all: fused weight transpose/tile + activation cvt + LoRA stage-1 ----------------
// bid < 1024: weight-tile block (kt = bid&15, nb = (bid>>4)&15, wsel = bid>>8):
//   W fp32 [K][N] -> tiled swizzled fp16 [nb][kt][row][chunk]; linear slot (r,c) holds
//   source chunk (c ^ (r&7)) so GEMM staging is a pure linear DMA.
// bid >= 1024: activation block (idx = bid-1024; mblk = idx&1023, y = idx>>10):
//   y=0: q -> xaq + q16 (slot 0). y=1: v -> xav + v16 (slot 2). y=2: k -> k16 (slot 1).
__global__ __launch_bounds__(256) void prep_all(const float* __restrict__ q, const float* __restrict__ kk,
                                                const float* __restrict__ v,
                                                const float* __restrict__ w0, const float* __restrict__ w1,
                                                const float* __restrict__ w2, const float* __restrict__ w3,
                                                const float* __restrict__ wqa, const float* __restrict__ wva,
                                                float* __restrict__ xaq, float* __restrict__ xav,
                                                _Float16* __restrict__ th, _Float16* __restrict__ o16) {
    __shared__ float t[64][65];
    const int bid = blockIdx.x;
    const int tid = threadIdx.x;
    if (bid < 1024) {
        const int kt = bid & 15, nb = (bid >> 4) & 15, z = bid >> 8;
        const float* W = z == 0 ? w0 : z == 1 ? w1 : z == 2 ? w2 : w3;
        _Float16* oh = th + (size_t)z * 1048576;
        const int k0 = kt * 64, n0 = nb * 64;
        const int c = tid & 15, r = tid >> 4;
#pragma unroll
        for (int i = 0; i < 4; ++i) {
            const int row = r + i * 16;  // k-local
            const float4 v4 = *(const float4*)&W[(size_t)(k0 + row) * 1024 + n0 + c * 4];
            t[c * 4 + 0][row] = v4.x;
            t[c * 4 + 1][row] = v4.y;
            t[c * 4 + 2][row] = v4.z;
            t[c * 4 + 3][row] = v4.w;
        }
        __syncthreads();
        const size_t tb = (size_t)(nb * 16 + kt) * 4096;
#pragma unroll
        for (int i = 0; i < 2; ++i) {
            const int cid = tid * 2 + i;
            const int rr = cid >> 3, cc = cid & 7;
            const int ksrc = (cc ^ (rr & 7)) * 8;
            f16x8 hv;
#pragma unroll
            for (int j = 0; j < 8; ++j) hv[j] = (_Float16)t[rr][ksrc + j];
            *(f16x8*)&oh[tb + cid * 8] = hv;
        }
    } else {
        const int idx = bid - 1024;
        const int mblk = idx & 1023, y = idx >> 10;
        const float* X = y == 0 ? q : y == 1 ? v : kk;
        _Float16* O = o16 + (size_t)(y == 0 ? 0 : y == 1 ? 2 : 1) * 4194304;
        const float* WA = y == 0 ? wqa : wva;
        float* XA = y == 0 ? xaq : xav;
        const int w = tid >> 6, lane = tid & 63;
        const int m = mblk * 4 + w;
        const float* xrow = X + (size_t)m * 1024;
        _Float16* orow = O + (size_t)m * 1024;
        float s[8] = {};
#pragma unroll
        for (int i = 0; i < 4; ++i) {
            const int k = lane * 4 + i * 256;
            const float4 x4 = *(const float4*)&xrow[k];
            *(f16x4*)&orow[k] = pack4(x4.x, x4.y, x4.z, x4.w);
            if (y < 2) {
                const float xs[4] = {x4.x, x4.y, x4.z, x4.w};
#pragma unroll
                for (int j = 0; j < 4; ++j) {
                    const float* wr = WA + (size_t)(k + j) * 8;
                    const float xv = xs[j];
#pragma unroll
                    for (int rr = 0; rr < 8; ++rr) s[rr] = fmaf(xv, wr[rr], s[rr]);
                }
            }
        }
        if (y < 2) {
#pragma unroll
            for (int rr = 0; rr < 8; ++rr) {
                float vv = s[rr];
                vv += __shfl_xor(vv, 32);
                vv += __shfl_xor(vv, 16);
                vv += __shfl_xor(vv, 8);
                vv += __shfl_xor(vv, 4);
                vv += __shfl_xor(vv, 2);
                vv += __shfl_xor(vv, 1);
                if (lane == 0) XA[(size_t)m * 8 + rr] = vv;
            }
        }
    }
}

// ---------------- merged QKV GEMM (r18 verified, unchanged) ----------------
// z=0: q16 -> qhF (fp16 [B,H,S,D], LoRA, pre-scaled). z=1: k16 -> khF (no LoRA).
// z=2: v16 -> vTF (fp16 [B,H,D,S], LoRA). Grid (64,16,3).
__global__ __launch_bounds__(256) void qkv_gemm(const _Float16* __restrict__ a16,
                                                const _Float16* __restrict__ Wt,
                                                const float* __restrict__ bq, const float* __restrict__ bk,
                                                const float* __restrict__ bv,
                                                const float* __restrict__ xaq, const float* __restrict__ xav,
                                                const float* __restrict__ wqb, const float* __restrict__ wvb,
                                                float qscale,
                                                _Float16* __restrict__ qhF, _Float16* __restrict__ khF,
                                                _Float16* __restrict__ vTF) {
    const int z = blockIdx.z;
    const _Float16* A = a16 + (size_t)z * 4194304;
    const _Float16* Bt = Wt + (size_t)z * 1048576;
    const float* bias = z == 0 ? bq : z == 1 ? bk : bv;
    const float* XA = z == 0 ? xaq : xav;
    const float* WB = z == 0 ? wqb : wvb;
    const float scale = z == 0 ? qscale : 1.f;
    const bool lora = (z != 1);
    _Float16* outp = z == 0 ? qhF : z == 1 ? khF : vTF;

    __shared__ _Float16 Ahs[2][4096], Bhs[2][4096];
    const int tid = threadIdx.x;
    const int w = tid >> 6, l = tid & 63;
    const int lm = l & 15, g = l >> 4;
    const int wm = w >> 1, wn = w & 1;
    const int m0 = blockIdx.x * 64, nb = blockIdx.y;

    const int lr = l >> 3;
    const int ksw = ((l & 7) ^ lr) * 8;
    const _Float16* Asrc0 = A + (size_t)(m0 + w * 16 + lr) * 1024 + ksw;
    const _Float16* Asrc1 = A + (size_t)(m0 + w * 16 + 8 + lr) * 1024 + ksw;
    const _Float16* Bsrc0 = Bt + (size_t)nb * 65536 + (w * 128 + l) * 8;
    const _Float16* Bsrc1 = Bt + (size_t)nb * 65536 + (w * 128 + 64 + l) * 8;
    const int adst0 = w * 1024, adst1 = w * 1024 + 512;

    int afo[2][2], bfo[2][2];
#pragma unroll
    for (int t = 0; t < 2; ++t)
#pragma unroll
        for (int kc = 0; kc < 2; ++kc) {
            const int ar = wm * 32 + t * 16 + lm;
            const int br = wn * 32 + t * 16 + lm;
            afo[t][kc] = ar * 64 + (((kc * 4 + g) ^ (ar & 7)) * 8);
            bfo[t][kc] = br * 64 + (((kc * 4 + g) ^ (br & 7)) * 8);
        }

    f32x4 acc[2][2] = {};

#define STAGE(buf, kt)                                  \
    {                                                   \
        const int ko = (kt) * 64;                       \
        const int bo = (kt) * 4096;                     \
        gll16(Asrc0 + ko, &Ahs[buf][adst0]);            \
        gll16(Asrc1 + ko, &Ahs[buf][adst1]);            \
        gll16(Bsrc0 + bo, &Bhs[buf][adst0]);            \
        gll16(Bsrc1 + bo, &Bhs[buf][adst1]);            \
    }

    STAGE(0, 0)
    __syncthreads();

    for (int kt = 0; kt < 16; ++kt) {
        const int cur = kt & 1;
        if (kt < 15) STAGE(cur ^ 1, kt + 1)
        const _Float16* Ac = &Ahs[cur][0];
        const _Float16* Bc = &Bhs[cur][0];
#pragma unroll
        for (int kc = 0; kc < 2; ++kc) {
            f16x8 ah[2], bh[2];
#pragma unroll
            for (int i = 0; i < 2; ++i) {
                ah[i] = *(const f16x8*)&Ac[afo[i][kc]];
                bh[i] = *(const f16x8*)&Bc[bfo[i][kc]];
            }
            __builtin_amdgcn_s_setprio(1);
#pragma unroll
            for (int mt = 0; mt < 2; ++mt)
#pragma unroll
                for (int nt = 0; nt < 2; ++nt)
                    acc[mt][nt] = __builtin_amdgcn_mfma_f32_16x16x32_f16(ah[mt], bh[nt], acc[mt][nt], 0, 0, 0);
            __builtin_amdgcn_s_setprio(0);
        }
        __syncthreads();
    }
#undef STAGE

    const int nbase = nb * 64 + wn * 32;
    const int head = nb;
    float bias2[2];
#pragma unroll
    for (int nt = 0; nt < 2; ++nt) bias2[nt] = bias[nbase + nt * 16 + lm];
    float wbv[8][2];
    if (lora) {
#pragma unroll
        for (int rr = 0; rr < 8; ++rr)
#pragma unroll
            for (int nt = 0; nt < 2; ++nt) wbv[rr][nt] = WB[rr * 1024 + nbase + nt * 16 + lm];
    }
#pragma unroll
    for (int mt = 0; mt < 2; ++mt) {
        float ov[2][4];
#pragma unroll
        for (int r = 0; r < 4; ++r) {
            const int m = m0 + wm * 32 + mt * 16 + g * 4 + r;
            float xa8[8];
            if (lora) {
#pragma unroll
                for (int rr = 0; rr < 8; ++rr) xa8[rr] = XA[(size_t)m * 8 + rr];
            }
#pragma unroll
            for (int nt = 0; nt < 2; ++nt) {
                float o = acc[mt][nt][r] + bias2[nt];
                if (lora) {
#pragma unroll
                    for (int rr = 0; rr < 8; ++rr) o = fmaf(xa8[rr], wbv[rr][nt], o);
                }
                o *= scale;
                ov[nt][r] = o;
                if (z != 2) {
                    const int b = m >> 11, s = m & 2047;
                    outp[((size_t)(b * 16 + head) * 2048 + s) * 64 + wn * 32 + nt * 16 + lm] = (_Float16)o;
                }
            }
        }
        if (z == 2) {
            const int b = m0 >> 11;
            const int sb = (m0 & 2047) + wm * 32 + mt * 16 + g * 4;
#pragma unroll
            for (int nt = 0; nt < 2; ++nt) {
                const int d = wn * 32 + nt * 16 + lm;
                const f16x4 pv = pack4(ov[nt][0], ov[nt][1], ov[nt][2], ov[nt][3]);
                *(f16x4*)&outp[((size_t)(b * 16 + head) * 64 + d) * 2048 + sb] = pv;
            }
        }
    }
}

// ---------------- output-projection GEMM (r18 verified, unchanged) ----------------
__global__ __launch_bounds__(256) void gemm_wo(const _Float16* __restrict__ A,
                                               const _Float16* __restrict__ Bt,
                                               const float* __restrict__ bias,
                                               float* __restrict__ outp) {
    __shared__ _Float16 Ahs[2][4096], Bhs[2][4096];
    const int tid = threadIdx.x;
    const int w = tid >> 6, l = tid & 63;
    const int lm = l & 15, g = l >> 4;
    const int wm = w >> 1, wn = w & 1;
    const int m0 = blockIdx.x * 64, nb = blockIdx.y;

    const int lr = l >> 3;
    const int ksw = ((l & 7) ^ lr) * 8;
    const _Float16* Asrc0 = A + (size_t)(m0 + w * 16 + lr) * 1024 + ksw;
    const _Float16* Asrc1 = A + (size_t)(m0 + w * 16 + 8 + lr) * 1024 + ksw;
    const _Float16* Bsrc0 = Bt + (size_t)nb * 65536 + (w * 128 + l) * 8;
    const _Float16* Bsrc1 = Bt + (size_t)nb * 65536 + (w * 128 + 64 + l) * 8;
    const int adst0 = w * 1024, adst1 = w * 1024 + 512;

    int afo[2][2], bfo[2][2];
#pragma unroll
    for (int t = 0; t < 2; ++t)
#pragma unroll
        for (int kc = 0; kc < 2; ++kc) {
            const int ar = wm * 32 + t * 16 + lm;
            const int br = wn * 32 + t * 16 + lm;
            afo[t][kc] = ar * 64 + (((kc * 4 + g) ^ (ar & 7)) * 8);
            bfo[t][kc] = br * 64 + (((kc * 4 + g) ^ (br & 7)) * 8);
        }

    f32x4 acc[2][2] = {};

#define STAGE(buf, kt)                                  \
    {                                                   \
        const int ko = (kt) * 64;                       \
        const int bo = (kt) * 4096;                     \
        gll16(Asrc0 + ko, &Ahs[buf][adst0]);            \
        gll16(Asrc1 + ko, &Ahs[buf][adst1]);            \
        gll16(Bsrc0 + bo, &Bhs[buf][adst0]);            \
        gll16(Bsrc1 + bo, &Bhs[buf][adst1]);            \
    }

    STAGE(0, 0)
    __syncthreads();

    for (int kt = 0; kt < 16; ++kt) {
        const int cur = kt & 1;
        if (kt < 15) STAGE(cur ^ 1, kt + 1)
        const _Float16* Ac = &Ahs[cur][0];
        const _Float16* Bc = &Bhs[cur][0];
#pragma unroll
        for (int kc = 0; kc < 2; ++kc) {
            f16x8 ah[2], bh[2];
#pragma unroll
            for (int i = 0; i < 2; ++i) {
                ah[i] = *(const f16x8*)&Ac[afo[i][kc]];
                bh[i] = *(const f16x8*)&Bc[bfo[i][kc]];
            }
            __builtin_amdgcn_s_setprio(1);
#pragma unroll
            for (int mt = 0; mt < 2; ++mt)
#pragma unroll
                for (int nt = 0; nt < 2; ++nt)
                    acc[mt][nt] = __builtin_amdgcn_mfma_f32_16x16x32_f16(ah[mt], bh[nt], acc[mt][nt], 0, 0, 0);
            __builtin_amdgcn_s_setprio(0);
        }
        __syncthreads();
    }
#undef STAGE

    const int nbase = nb * 64 + wn * 32;
    float bias2[2];
#pragma unroll
    for (int nt = 0; nt < 2; ++nt) bias2[nt] = bias[nbase + nt * 16 + lm];
#pragma unroll
    for (int mt = 0; mt < 2; ++mt) {
#pragma unroll
        for (int r = 0; r < 4; ++r) {
            const int m = m0 + wm * 32 + mt * 16 + g * 4 + r;
#pragma unroll
            for (int nt = 0; nt < 2; ++nt)
                outp[(size_t)m * 1024 + nbase + nt * 16 + lm] = acc[mt][nt][r] + bias2[nt];
        }
    }
}

// ---------------- flash attention v9 (r14/r16/r18 verified, unchanged) ----------------
__global__ __launch_bounds__(256, 2) void flash_attn9(const _Float16* __restrict__ qh,
                                                      const _Float16* __restrict__ kh,
                                                      const _Float16* __restrict__ vT,
                                                      _Float16* __restrict__ ao) {
    __shared__ _Float16 Ks[2][4096];  // [kv][d], 16B chunk ^= kv&7
    __shared__ _Float16 Vs[2][4096];  // [d][kv], 16B chunk ^= d&7
    const int tid = threadIdx.x;
    const int w = tid >> 6, l = tid & 63;
    const int m = l & 15, g = l >> 4;
    const int bh = blockIdx.x & 31, qt = blockIdx.x >> 5;
    const _Float16* Qb = qh + (size_t)bh * 131072;
    const _Float16* Kb = kh + (size_t)bh * 131072;
    const _Float16* Vb = vT + (size_t)bh * 131072;
    const int q0 = qt * 128 + w * 32;

    f16x8 qf[2][2];
#pragma unroll
    for (int qg = 0; qg < 2; ++qg) {
        const _Float16* qrow = Qb + (size_t)(q0 + qg * 16 + m) * 64 + g * 8;
        qf[qg][0] = *(const f16x8*)(qrow);
        qf[qg][1] = *(const f16x8*)(qrow + 32);
    }

    const int r0 = tid >> 3, c0 = tid & 7;
    const int r1 = (tid + 256) >> 3;
    const int kgl0 = r0 * 64 + c0 * 8;
    const int kgl1 = r1 * 64 + c0 * 8;
    const int kso0 = r0 * 64 + ((c0 ^ (r0 & 7)) * 8);
    const int kso1 = r1 * 64 + ((c0 ^ (r1 & 7)) * 8);
    const size_t vgl0 = (size_t)r0 * 2048 + c0 * 8;
    const size_t vgl1 = (size_t)r1 * 2048 + c0 * 8;

    int koff[4][2];
#pragma unroll
    for (int nt = 0; nt < 4; ++nt)
#pragma unroll
        for (int kc = 0; kc < 2; ++kc) {
            const int kv = nt * 16 + m;
            koff[nt][kc] = kv * 64 + (((kc * 4 + g) ^ (kv & 7)) * 8);
        }
    int voff[4][4];
#pragma unroll
    for (int dt = 0; dt < 4; ++dt)
#pragma unroll
        for (int nt = 0; nt < 4; ++nt) {
            const int d = dt * 16 + m;
            voff[dt][nt] = d * 64 + (((nt * 2 + (g >> 1)) ^ (d & 7)) * 8) + (g & 1) * 4;
        }

    f32x4 acc_o[2][4] = {};
    f32x4 acc_l[2] = {};
    const f16x4 onesf = {(_Float16)1.f, (_Float16)1.f, (_Float16)1.f, (_Float16)1.f};

    {
        const f16x8 ka = *(const f16x8*)(Kb + kgl0);
        const f16x8 kb2 = *(const f16x8*)(Kb + kgl1);
        const f16x8 va = *(const f16x8*)(Vb + vgl0);
        const f16x8 vb2 = *(const f16x8*)(Vb + vgl1);
        *(f16x8*)(&Ks[0][0] + kso0) = ka;
        *(f16x8*)(&Ks[0][0] + kso1) = kb2;
        *(f16x8*)(&Vs[0][0] + kso0) = va;
        *(f16x8*)(&Vs[0][0] + kso1) = vb2;
    }
    __syncthreads();

    for (int t = 0; t < 32; ++t) {
        const int cur = t & 1;
        f16x8 ka, kb2, va, vb2;
        if (t < 31) {
            const int koI = (t + 1) * 4096;
            const int voI = (t + 1) * 64;
            ka = *(const f16x8*)(Kb + koI + kgl0);
            kb2 = *(const f16x8*)(Kb + koI + kgl1);
            va = *(const f16x8*)(Vb + voI + vgl0);
            vb2 = *(const f16x8*)(Vb + voI + vgl1);
        }

        const _Float16* Kc = &Ks[cur][0];
        const _Float16* Vc = &Vs[cur][0];

        f32x4 s[2][4] = {};
        __builtin_amdgcn_s_setprio(1);
#pragma unroll
        for (int nt = 0; nt < 4; ++nt)
#pragma unroll
            for (int kc = 0; kc < 2; ++kc) {
                const f16x8 kf = *(const f16x8*)(Kc + koff[nt][kc]);
                s[0][nt] = __builtin_amdgcn_mfma_f32_16x16x32_f16(kf, qf[0][kc], s[0][nt], 0, 0, 0);
                s[1][nt] = __builtin_amdgcn_mfma_f32_16x16x32_f16(kf, qf[1][kc], s[1][nt], 0, 0, 0);
            }
        __builtin_amdgcn_s_setprio(0);

        f16x4 pf[2][4];
#pragma unroll
        for (int qg = 0; qg < 2; ++qg)
#pragma unroll
            for (int nt = 0; nt < 4; ++nt)
                pf[qg][nt] = pack4(exp2f(s[qg][nt][0]), exp2f(s[qg][nt][1]),
                                   exp2f(s[qg][nt][2]), exp2f(s[qg][nt][3]));

        __builtin_amdgcn_s_setprio(1);
#pragma unroll
        for (int nt = 0; nt < 4; ++nt) {
            acc_l[0] = __builtin_amdgcn_mfma_f32_16x16x16f16(onesf, pf[0][nt], acc_l[0], 0, 0, 0);
            acc_l[1] = __builtin_amdgcn_mfma_f32_16x16x16f16(onesf, pf[1][nt], acc_l[1], 0, 0, 0);
#pragma unroll
            for (int dt = 0; dt < 4; ++dt) {
                const f16x4 vf = *(const f16x4*)(Vc + voff[dt][nt]);
                acc_o[0][dt] = __builtin_amdgcn_mfma_f32_16x16x16f16(vf, pf[0][nt], acc_o[0][dt], 0, 0, 0);
                acc_o[1][dt] = __builtin_amdgcn_mfma_f32_16x16x16f16(vf, pf[1][nt], acc_o[1][dt], 0, 0, 0);
            }
        }
        __builtin_amdgcn_s_setprio(0);

        if (t < 31) {
            const int nxt = cur ^ 1;
            *(f16x8*)(&Ks[nxt][0] + kso0) = ka;
            *(f16x8*)(&Ks[nxt][0] + kso1) = kb2;
            *(f16x8*)(&Vs[nxt][0] + kso0) = va;
            *(f16x8*)(&Vs[nxt][0] + kso1) = vb2;
        }
        __syncthreads();
    }

    const int b = bh >> 4, h = bh & 15;
#pragma unroll
    for (int qg = 0; qg < 2; ++qg) {
        const float inv = 1.f / acc_l[qg][0];
        const int srow = q0 + qg * 16 + m;
        _Float16* orow = ao + ((size_t)(b * 2048 + srow)) * 1024 + h * 64;
#pragma unroll
        for (int dt = 0; dt < 4; ++dt) {
            const f16x4 o = pack4(acc_o[qg][dt][0] * inv, acc_o[qg][dt][1] * inv,
                                  acc_o[qg][dt][2] * inv, acc_o[qg][dt][3] * inv);
            *(f16x4*)&orow[dt * 16 + g * 4] = o;
        }
    }
}

extern "C" void kernel_launch(void* const* d_in, const int* in_sizes, int n_in,
                              void* d_out, int out_size, void* d_ws, size_t ws_size,
                              hipStream_t stream) {
    const float* q    = (const float*)d_in[0];
    const float* k    = (const float*)d_in[1];
    const float* v    = (const float*)d_in[2];
    const float* wq   = (const float*)d_in[3];
    const float* bq   = (const float*)d_in[4];
    const float* wq_a = (const float*)d_in[5];
    const float* wq_b = (const float*)d_in[6];
    const float* wk   = (const float*)d_in[7];
    const float* bk   = (const float*)d_in[8];
    const float* wv   = (const float*)d_in[9];
    const float* bv   = (const float*)d_in[10];
    const float* wv_a = (const float*)d_in[11];
    const float* wv_b = (const float*)d_in[12];
    const float* wo   = (const float*)d_in[13];
    const float* bo   = (const float*)d_in[14];
    float* out = (float*)d_out;

    char* wsb = (char*)d_ws;
    _Float16* Wt   = (_Float16*)(wsb);                  // 8 MB: 4x tiled fp16 weights
    _Float16* a16  = (_Float16*)(wsb + (8u << 20));     // 24 MB: q16/k16/v16 fp16 [4096][1024]
    _Float16* aoF  = a16;                               // reuse q16 slot after Q-GEMM (dead)
    _Float16* qhF  = (_Float16*)(wsb + (32u << 20));    // 8 MB [B,H,S,D]
    _Float16* khF  = (_Float16*)(wsb + (40u << 20));    // 8 MB [B,H,S,D]
    _Float16* vTF  = (_Float16*)(wsb + (48u << 20));    // 8 MB [B,H,D,S]
    float* xaq     = (float*)(wsb + (56u << 20));       // 128 KB
    float* xav     = (float*)(wsb + (56u << 20) + (128u << 10));

    const float qscale = 0.18033688f;  // (1/8) * log2(e)

    prep_all<<<4096, 256, 0, stream>>>(q, k, v, wq, wk, wv, wo, wq_a, wv_a,
                                       xaq, xav, Wt, a16);

    qkv_gemm<<<dim3(64, 16, 3), 256, 0, stream>>>(a16, Wt, bq, bk, bv, xaq, xav,
                                                  wq_b, wv_b, qscale, qhF, khF, vTF);

    flash_attn9<<<512, 256, 0, stream>>>(qhF, khF, vTF, aoF);

    gemm_wo<<<dim3(64, 16), 256, 0, stream>>>(aoF, Wt + 3145728, bo, out);
}